// Round 7
// baseline (309.507 us; speedup 1.0000x reference)
//
#include <hip/hip_runtime.h>
#include <hip/hip_bf16.h>

#define RES 300
#define NPLANE (RES * RES)   // 90000
#define NC_A 48
#define APP_DIM 27
#define KDIM 144             // 3 * NC_A
#define KS 168               // prod LDS row stride in shorts (336 B, 16B-aligned)
#define CWS 20               // cw floats per sample (18 data + orig + pad)

#define PT_TILES 352         // ceil(90000/256) p-tiles per plane
#define NPBLK (3 * PT_TILES) // 1056 plane-transpose blocks
#define LSS 268              // LDS short-stride per channel row (536 B, 8B-aligned)
#define NBUCK 4096           // 12-bit morton buckets

typedef __attribute__((ext_vector_type(2))) float f32x2;
typedef __attribute__((ext_vector_type(4))) float f32x4;
typedef __attribute__((ext_vector_type(8))) short short8;

// bf16 (packed in uint halves) -> f32
__device__ __forceinline__ float bf_lo(unsigned int u) { return __uint_as_float(u << 16); }
__device__ __forceinline__ float bf_hi(unsigned int u) { return __uint_as_float(u & 0xffff0000u); }
__device__ __forceinline__ unsigned int packbf2(float a, float b) {
  __hip_bfloat162 h;
  h.x = __float2bfloat16(a);
  h.y = __float2bfloat16(b);
  return *(unsigned int*)&h;
}

__device__ __forceinline__ int bucket_of(float x, float y, float z) {
  int bx = min(max((int)((x + 1.f) * 8.f), 0), 15);
  int by = min(max((int)((y + 1.f) * 8.f), 0), 15);
  int bz = min(max((int)((z + 1.f) * 8.f), 0), 15);
  int m = 0;
  #pragma unroll
  for (int i = 0; i < 4; ++i)
    m |= (((bx >> i) & 1) << (3 * i)) | (((by >> i) & 1) << (3 * i + 1)) |
         (((bz >> i) & 1) << (3 * i + 2));
  return m;
}

// ---------------------------------------------------------------------------
// Prep kernel (R5 structure): plane transpose -> Tp (3,90000,64) bf16,
// line -> TlP (3,300,64) packed bf16x2 (y,y+1), basis_W -> MFMA B-frags.
// ---------------------------------------------------------------------------
__global__ __launch_bounds__(256) void prep(
    const float* __restrict__ plane, const float* __restrict__ line,
    const float* __restrict__ W,
    unsigned int* __restrict__ Tp, unsigned int* __restrict__ TlP,
    __hip_bfloat16* __restrict__ Wg) {
  __shared__ unsigned short ls[64 * LSS];
  const int blk = blockIdx.x;
  const int tid = threadIdx.x;

  if (blk < NPBLK) {
    const int i    = blk / PT_TILES;
    const int p0   = (blk % PT_TILES) * 256;
    const int l    = tid & 63;
    const int w    = tid >> 6;
    const int pl   = p0 + 4 * l;
    const bool pok = (pl + 3) < NPLANE;
    #pragma unroll
    for (int r = 0; r < 16; ++r) {
      int c = w * 16 + r;
      float4 v = make_float4(0.f, 0.f, 0.f, 0.f);
      if (pok) v = *(const float4*)&plane[(size_t)(i * 64 + c) * NPLANE + pl];
      uint2 u;
      u.x = packbf2(v.x, v.y);
      u.y = packbf2(v.z, v.w);
      *(uint2*)&ls[c * LSS + 4 * l] = u;
    }
    __syncthreads();
    const size_t ob = ((size_t)i * NPLANE + p0) * 32;   // uint units
    const int plim = min(256, NPLANE - p0);
    #pragma unroll
    for (int r = 0; r < 8; ++r) {
      int flat4 = r * 256 + tid;
      int p  = flat4 >> 3;
      int c0 = (flat4 & 7) * 8;
      if (p < plim) {
        unsigned int x0 = (unsigned int)ls[(c0 + 0) * LSS + p] |
                          ((unsigned int)ls[(c0 + 1) * LSS + p] << 16);
        unsigned int x1 = (unsigned int)ls[(c0 + 2) * LSS + p] |
                          ((unsigned int)ls[(c0 + 3) * LSS + p] << 16);
        unsigned int x2 = (unsigned int)ls[(c0 + 4) * LSS + p] |
                          ((unsigned int)ls[(c0 + 5) * LSS + p] << 16);
        unsigned int x3 = (unsigned int)ls[(c0 + 6) * LSS + p] |
                          ((unsigned int)ls[(c0 + 7) * LSS + p] << 16);
        uint4 o = {x0, x1, x2, x3};
        *(uint4*)&Tp[ob + (size_t)p * 32 + c0 / 2] = o;
      }
    }
  } else if (blk < NPBLK + 15) {
    unsigned int* ltile = (unsigned int*)ls;
    const int b  = blk - NPBLK;
    const int i  = b / 5;
    const int y0 = (b % 5) * 64;
    const int yl = tid & 63;
    const int cq = tid >> 6;
    #pragma unroll
    for (int k = 0; k < 16; ++k) {
      int c = cq * 16 + k;
      int y = y0 + yl;
      float a = 0.f, bv = 0.f;
      if (y < RES) {
        const float* row = line + (i * 64 + c) * RES;
        a  = row[y];
        bv = row[min(y + 1, RES - 1)];
      }
      ltile[yl * 65 + c] = packbf2(a, bv);
    }
    __syncthreads();
    #pragma unroll
    for (int k = 0; k < 16; ++k) {
      int ylc = k * 4 + cq;
      int c   = tid & 63;
      int y   = y0 + ylc;
      if (y < RES) TlP[((size_t)i * RES + y) * 64 + c] = ltile[ylc * 65 + c];
    }
  } else {
    for (int idx = tid; idx < 2 * 5 * 64 * 8; idx += 256) {
      int j    = idx & 7;
      int lane = (idx >> 3) & 63;
      int kt   = (idx >> 9) % 5;
      int tile = idx / (5 * 64 * 8);
      int n = tile * 16 + (lane & 15);
      int k = kt * 32 + (lane >> 4) * 8 + j;
      float v = (n < APP_DIM && k < KDIM) ? W[n * KDIM + k] : 0.f;
      Wg[idx] = __float2bfloat16(v);
    }
  }
}

// ---------------------------------------------------------------------------
// Sort kernels: zero hist -> histogram -> exclusive scan -> scatter
// ---------------------------------------------------------------------------
__global__ __launch_bounds__(256) void k_zero(int* __restrict__ hist) {
  int i = blockIdx.x * 256 + threadIdx.x;
  if (i < NBUCK) hist[i] = 0;
}

__global__ __launch_bounds__(256) void k_hist(
    const float* __restrict__ xyz, int* __restrict__ hist, int n_total) {
  int n = blockIdx.x * 256 + threadIdx.x;
  if (n < n_total) {
    int b = bucket_of(xyz[3 * n], xyz[3 * n + 1], xyz[3 * n + 2]);
    atomicAdd(&hist[b], 1);
  }
}

__global__ __launch_bounds__(1024) void k_scan(int* __restrict__ hist) {
  __shared__ int sd[1024];
  const int tid = threadIdx.x;
  int carry = 0;
  for (int ch = 0; ch < NBUCK / 1024; ++ch) {
    int i = ch * 1024 + tid;
    int v = hist[i];
    sd[tid] = v;
    __syncthreads();
    #pragma unroll
    for (int off = 1; off < 1024; off <<= 1) {
      int t = (tid >= off) ? sd[tid - off] : 0;
      __syncthreads();
      sd[tid] += t;
      __syncthreads();
    }
    int incl = sd[tid];
    int total = sd[1023];
    hist[i] = incl - v + carry;   // exclusive + carry
    carry += total;
    __syncthreads();
  }
}

__global__ __launch_bounds__(256) void k_scatter(
    const float* __restrict__ xyz, int* __restrict__ hist,
    float4* __restrict__ xyzP, int n_total) {
  int n = blockIdx.x * 256 + threadIdx.x;
  if (n < n_total) {
    float x = xyz[3 * n], y = xyz[3 * n + 1], z = xyz[3 * n + 2];
    int b = bucket_of(x, y, z);
    int pos = atomicAdd(&hist[b], 1);
    xyzP[pos] = make_float4(x, y, z, __int_as_float(n));
  }
}

// ---------------------------------------------------------------------------
// Main kernel: fused gather + blend + sigma + MFMA projection.
// SORTED=1: reads morton-permuted xyzP (float4: x,y,z,orig); outputs written
// via orig index. 256 thr (4 waves), 64 samples/block; half-wave per sample,
// lane = channel pair; 15 batched VMEM gathers per 2-sample iteration.
// LDS = 21504 (prod) + 5120 (cw) = 26624 B -> 6 blocks/CU.
// ---------------------------------------------------------------------------
template <bool SORTED>
__global__ __launch_bounds__(256, 6) void tensorf_main(
    const float* __restrict__ xyz, const float4* __restrict__ xyzP,
    const unsigned int* __restrict__ TpU, const unsigned int* __restrict__ TlP,
    const __hip_bfloat16* __restrict__ Wg,
    float* __restrict__ out, int n_total) {
  __shared__ __hip_bfloat16 prod[64 * KS];
  __shared__ float cw[64 * CWS];

  const int tid  = threadIdx.x;
  const int lane = tid & 63;
  const int wave = tid >> 6;
  const int n0   = blockIdx.x * 64;

  // zero prod k-pad [144,168)
  for (int j = tid; j < 64 * 12; j += 256) {
    int s = j / 12, kk = (j % 12) * 2;
    *(unsigned int*)&prod[s * KS + KDIM + kk] = 0u;
  }

  // Phase 0: per-sample precompute — packed cell/line index + 4 bilinear
  // weights + line weight + orig output index.
  if (tid < 64) {
    int n = min(n0 + tid, n_total - 1);
    float crd[3];
    int orig;
    if (SORTED) {
      float4 q = xyzP[n];
      crd[0] = q.x; crd[1] = q.y; crd[2] = q.z;
      orig = __float_as_int(q.w);
    } else {
      crd[0] = xyz[3 * n]; crd[1] = xyz[3 * n + 1]; crd[2] = xyz[3 * n + 2];
      orig = n;
    }
    const int m0s[3] = {0, 0, 1}, m1s[3] = {1, 2, 2}, vms[3] = {2, 1, 0};
    float* c = &cw[tid * CWS];
    #pragma unroll
    for (int i = 0; i < 3; ++i) {
      float ix = fminf(fmaxf((crd[m0s[i]] + 1.f) * 149.5f, 0.f), 299.f);
      float iy = fminf(fmaxf((crd[m1s[i]] + 1.f) * 149.5f, 0.f), 299.f);
      float ly = fminf(fmaxf((crd[vms[i]] + 1.f) * 149.5f, 0.f), 299.f);
      float x0f = fminf(floorf(ix), 298.f);
      float y0f = fminf(floorf(iy), 298.f);
      float l0f = fminf(floorf(ly), 298.f);
      float wx = ix - x0f, wy = iy - y0f, lwy = ly - l0f;
      int cell = i * NPLANE + (int)y0f * RES + (int)x0f;   // < 2^19
      int lidx = i * RES + (int)l0f;                       // < 2^10
      c[i * 6 + 0] = __int_as_float(cell | (lidx << 19));
      c[i * 6 + 1] = (1.f - wx) * (1.f - wy);
      c[i * 6 + 2] = wx * (1.f - wy);
      c[i * 6 + 3] = (1.f - wx) * wy;
      c[i * 6 + 4] = wx * wy;
      c[i * 6 + 5] = lwy;
    }
    c[18] = __int_as_float(orig);
  }
  __syncthreads();

  // Phase 1: gather + blend; 2 samples/wave-iteration, lane = channel pair
  const int cl   = lane & 31;
  const int half = lane >> 5;
  const int c2   = cl * 2;
  #pragma unroll 2
  for (int it = 0; it < 8; ++it) {
    int s = wave * 16 + it * 2 + half;
    const float* cp = &cw[s * CWS];

    // -- batched load phase: issue all 15 VMEM ops before any use
    unsigned int u00[3], u01[3], u10[3], u11[3];
    uint2 ul[3];
    float wgt[3][5];
    #pragma unroll
    for (int i = 0; i < 3; ++i) {
      float2 q0 = *(const float2*)&cp[i * 6];       // pack, w00
      float2 q1 = *(const float2*)&cp[i * 6 + 2];   // w01, w10
      float2 q2 = *(const float2*)&cp[i * 6 + 4];   // w11, lwy
      int pk   = __float_as_int(q0.x);
      int cell = pk & 0x7FFFF;
      int lidx = pk >> 19;
      int bidx = cell * 32 + cl;                    // uint index into TpU
      u00[i] = TpU[bidx];
      u01[i] = TpU[bidx + 32];
      u10[i] = TpU[bidx + RES * 32];
      u11[i] = TpU[bidx + RES * 32 + 32];
      ul[i]  = *(const uint2*)&TlP[(lidx << 6) + c2];
      wgt[i][0] = q0.y; wgt[i][1] = q1.x; wgt[i][2] = q1.y;
      wgt[i][3] = q2.x; wgt[i][4] = q2.y;
    }

    // -- blend phase
    float dsum = 0.f;
    #pragma unroll
    for (int i = 0; i < 3; ++i) {
      float pf_l = wgt[i][0] * bf_lo(u00[i]) + wgt[i][1] * bf_lo(u01[i]) +
                   wgt[i][2] * bf_lo(u10[i]) + wgt[i][3] * bf_lo(u11[i]);
      float pf_h = wgt[i][0] * bf_hi(u00[i]) + wgt[i][1] * bf_hi(u01[i]) +
                   wgt[i][2] * bf_hi(u10[i]) + wgt[i][3] * bf_hi(u11[i]);
      float lal = bf_lo(ul[i].x), lbl = bf_hi(ul[i].x);
      float lah = bf_lo(ul[i].y), lbh = bf_hi(ul[i].y);
      float lf_l = lal + wgt[i][4] * (lbl - lal);
      float lf_h = lah + wgt[i][4] * (lbh - lah);
      float prl = pf_l * lf_l, prh = pf_h * lf_h;
      if (cl < 24) {
        *(unsigned int*)&prod[s * KS + i * NC_A + c2] = packbf2(prl, prh);
      } else {
        dsum += prl + prh;    // density channel pairs 48..62
      }
    }
    dsum += __shfl_xor(dsum, 1);
    dsum += __shfl_xor(dsum, 2);
    dsum += __shfl_xor(dsum, 4);
    if (cl == 24) {
      int orig = __float_as_int(cw[s * CWS + 18]);
      out[orig] = dsum;       // duplicates (tail clamp) write same value
    }
  }
  __syncthreads();

  // Phase 2: app = prod(64x144) @ W^T via mfma 16x16x32 bf16, B from Wg
  const int srow = lane & 15, quad = lane >> 4;
  f32x4 acc0 = {0.f, 0.f, 0.f, 0.f}, acc1 = {0.f, 0.f, 0.f, 0.f};
  const short* prodS = (const short*)prod;
  const short* WgS   = (const short*)Wg;
  const int arow = (wave * 16 + srow) * KS;
  #pragma unroll
  for (int kt = 0; kt < 5; ++kt) {
    short8 a  = *(const short8*)&prodS[arow + kt * 32 + quad * 8];
    short8 b0 = *(const short8*)&WgS[(kt * 64 + lane) * 8];
    short8 b1 = *(const short8*)&WgS[((5 + kt) * 64 + lane) * 8];
    acc0 = __builtin_amdgcn_mfma_f32_16x16x32_bf16(a, b0, acc0, 0, 0, 0);
    acc1 = __builtin_amdgcn_mfma_f32_16x16x32_bf16(a, b1, acc1, 0, 0, 0);
  }
  // C/D layout: col(d) = lane&15, row(sample) = quad*4 + reg
  float* outApp = out + n_total;
  #pragma unroll
  for (int r = 0; r < 4; ++r) {
    int sr = wave * 16 + quad * 4 + r;
    int orig = __float_as_int(cw[sr * CWS + 18]);
    outApp[(size_t)orig * APP_DIM + srow] = acc0[r];
    if (srow < APP_DIM - 16)
      outApp[(size_t)orig * APP_DIM + 16 + srow] = acc1[r];
  }
}

// ---------------------------------------------------------------------------
extern "C" void kernel_launch(void* const* d_in, const int* in_sizes, int n_in,
                              void* d_out, int out_size, void* d_ws, size_t ws_size,
                              hipStream_t stream) {
  const float* xyz   = (const float*)d_in[0];
  const float* plane = (const float*)d_in[1];
  const float* line  = (const float*)d_in[2];
  const float* W     = (const float*)d_in[3];
  float* out = (float*)d_out;
  const int N = in_sizes[0] / 3;

  const size_t tp_b   = (size_t)3 * NPLANE * 128;   // 34,560,000
  const size_t tl_b   = 230400;
  const size_t wg_b   = 10240 + 5888;               // pad to 16,128 -> align
  const size_t hist_b = (size_t)NBUCK * 4;          // 16,384
  const size_t xyzp_b = (size_t)N * 16;             // 8,000,000

  char* ws = (char*)d_ws;
  unsigned int*   Tp   = (unsigned int*)ws;
  unsigned int*   TlP  = (unsigned int*)(ws + tp_b);
  __hip_bfloat16* Wg   = (__hip_bfloat16*)(ws + tp_b + tl_b);
  int*            hist = (int*)(ws + tp_b + tl_b + wg_b);
  float4*         xyzP = (float4*)(ws + tp_b + tl_b + wg_b + hist_b);

  const bool sorted = ws_size >= tp_b + tl_b + wg_b + hist_b + xyzp_b;
  const int nblk = (N + 255) / 256;

  prep<<<NPBLK + 16, 256, 0, stream>>>(plane, line, W, Tp, TlP, Wg);
  if (sorted) {
    k_zero<<<(NBUCK + 255) / 256, 256, 0, stream>>>(hist);
    k_hist<<<nblk, 256, 0, stream>>>(xyz, hist, N);
    k_scan<<<1, 1024, 0, stream>>>(hist);
    k_scatter<<<nblk, 256, 0, stream>>>(xyz, hist, xyzP, N);
    tensorf_main<true><<<(N + 63) / 64, 256, 0, stream>>>(
        xyz, xyzP, Tp, TlP, Wg, out, N);
  } else {
    tensorf_main<false><<<(N + 63) / 64, 256, 0, stream>>>(
        xyz, nullptr, Tp, TlP, Wg, out, N);
  }
}